// Round 12
// baseline (511.447 us; speedup 1.0000x reference)
//
#include <hip/hip_runtime.h>

#define N_NODES 100000
#define W_INF   256
#define W_OUTF  64
#define C_CH    2
#define T_ET    4
#define E_EDGE  800000
#define NUM_CLS 4
#define M_TGT   20000
#define BETA    0.5f
#define MAXDEG  96

typedef __attribute__((ext_vector_type(8))) short bf16x8;
typedef __attribute__((ext_vector_type(4))) float floatx4;

__device__ inline short f2bf(float f) {
    unsigned u = __builtin_bit_cast(unsigned, f);
    u += 0x7FFF + ((u >> 16) & 1);          // RNE
    return (short)(u >> 16);
}
// packed dword q = (bf16 ch0) | (bf16 ch1 << 16)
__device__ inline float bflo(unsigned q) { return __builtin_bit_cast(float, q << 16); }
__device__ inline float bfhi(unsigned q) { return __builtin_bit_cast(float, q & 0xFFFF0000u); }

// ---------- setup: softmax(filt) + Bt convert + mark rid + zero scalars ----------
__global__ void setup_kernel(const float* __restrict__ Ws,
                             const float* __restrict__ conv_weight,
                             const int* __restrict__ target_x,
                             short* __restrict__ Bt, float* __restrict__ filt,
                             int* __restrict__ rid, int* __restrict__ nrows,
                             float* __restrict__ out) {
    int i = blockIdx.x * 256 + threadIdx.x;
    if (i == 0) { nrows[0] = 0; nrows[1] = 0; out[0] = 0.f; }   // [1] = work queue
    if (i < C_CH) {
        int c = i;
        float mx = -1e30f;
        for (int t = 0; t < T_ET; t++) mx = fmaxf(mx, conv_weight[c * T_ET + t]);
        float e[T_ET];
        float s = 0.f;
        for (int t = 0; t < T_ET; t++) { e[t] = expf(conv_weight[c * T_ET + t] - mx); s += e[t]; }
        for (int t = 0; t < T_ET; t++) filt[c * T_ET + t] = e[t] / s;
    }
    if (i < C_CH * W_OUTF * W_INF) {
        int co = i >> 8, k = i & 255;
        int c = co >> 6, o = co & 63;
        Bt[i] = f2bf(Ws[((size_t)c * W_INF + k) * W_OUTF + o]);
    }
    if (i < M_TGT) rid[target_x[i]] = -2;
}

// ---------- compact flagged rows (wave-aggregated atomic) + zero counts ----------
__global__ void compact_kernel(int* __restrict__ rid, int* __restrict__ row_list,
                               int* __restrict__ nrows, int* __restrict__ counts) {
    int n = blockIdx.x * blockDim.x + threadIdx.x;
    if (n < M_TGT) counts[n] = 0;          // consumed by fused build (next dispatch)
    int lane = threadIdx.x & 63;
    bool flag = (n < N_NODES) && (rid[n] == -2);
    unsigned long long mask = __ballot(flag);
    int base = 0;
    if (lane == 0 && mask) base = atomicAdd(nrows, __popcll(mask));
    base = __shfl(base, 0);
    if (flag) {
        int id = base + __popcll(mask & ((1ULL << lane) - 1ULL));
        rid[n] = id;
        row_list[id] = n;
    }
}

// ---------- fused: MFMA gemm (even blocks) + edge binning (odd blocks) ----------
// EXACT R9 config — PROVEN 73us; R10's barrier-free global-B variant DOUBLED
// to 147us (L2-latency per MFMA operand; LDS staging amortizes it, barriers
// were cheap). Five experiments bracket this structure as its local floor.
// (256,4) = 128-reg cap, spill-free. Even/odd gemm/build interleave (m114).
// Xp stored bf16, channel-interleaved: dword d = n*64 + o holds {ch0 lo, ch1 hi}.
#define GMT  64
#define BLDA2 136
#define GEMM_NB  ((N_NODES + GMT - 1) / GMT)      // 1563
#define BUILD_BX ((E_EDGE / 8 + 255) / 256)       // 391
#define BUILD_TOT (BUILD_BX * T_ET)               // 1564
__global__ __launch_bounds__(256, 4)
void fused_gemm_build(const float* __restrict__ X, const short* __restrict__ Bt,
                      short* __restrict__ Xp,
                      const int* __restrict__ edge_index,
                      const float* __restrict__ edge_value,
                      const int* __restrict__ rid,
                      int* __restrict__ counts,
                      unsigned long long* __restrict__ records) {
    __shared__ short Bl[64][BLDA2];    // 17.4 KB: 64 output-rows x 128 k per stage
    int tid = threadIdx.x;
    int bx = blockIdx.x;
    if ((bx & 1) == 0) {
        int g = bx >> 1;
        if (g >= GEMM_NB) return;
        int w = tid >> 6, lane = tid & 63;
        int quad = lane >> 4, l15 = lane & 15;
        int m0 = g * GMT + w * 16;
        int arow = m0 + l15;
        if (arow >= N_NODES) arow = N_NODES - 1;
        const float* xrow = X + (size_t)arow * W_INF;
        floatx4 acc[C_CH][4] = {};
        #pragma unroll 1
        for (int kh = 0; kh < 2; kh++) {          // K-half: addresses only
            // A strip for this K-half: 4 chunks x 8 bf16 = 16 VGPRs
            bf16x8 af[4];
            #pragma unroll
            for (int kc = 0; kc < 4; kc++) {
                int kb = kh * 128 + kc * 32 + quad * 8;
                float4 v0 = *(const float4*)&xrow[kb];
                float4 v1 = *(const float4*)&xrow[kb + 4];
                af[kc][0] = f2bf(v0.x); af[kc][1] = f2bf(v0.y);
                af[kc][2] = f2bf(v0.z); af[kc][3] = f2bf(v0.w);
                af[kc][4] = f2bf(v1.x); af[kc][5] = f2bf(v1.y);
                af[kc][6] = f2bf(v1.z); af[kc][7] = f2bf(v1.w);
            }
            #pragma unroll
            for (int c = 0; c < C_CH; c++) {      // fully unrolled: acc static
                if (kh | c) __syncthreads();      // protect re-stage
                // stage channel c, K-half kh: 64 rows x 128 k (1024 x 16B chunks)
                #pragma unroll
                for (int l = 0; l < 4; l++) {
                    int idx = tid + l * 256;
                    int r = idx >> 4;
                    int kp = (idx & 15) * 8;
                    *(bf16x8*)&Bl[r][kp] =
                        *(const bf16x8*)&Bt[(size_t)(c * 64 + r) * W_INF + kh * 128 + kp];
                }
                __syncthreads();
                #pragma unroll
                for (int kc = 0; kc < 4; kc++) {
                    int kb = kc * 32 + quad * 8;
                    #pragma unroll
                    for (int nt = 0; nt < 4; nt++) {
                        bf16x8 b = *(bf16x8*)&Bl[nt * 16 + l15][kb];
                        acc[c][nt] =
                            __builtin_amdgcn_mfma_f32_16x16x32_bf16(af[kc], b, acc[c][nt], 0, 0, 0);
                    }
                }
            }
        }
        // D layout: o = nt*16 + l15; m = m0 + quad*4 + r. Pack both channels.
        #pragma unroll
        for (int nt = 0; nt < 4; nt++) {
            int o = nt * 16 + l15;
            #pragma unroll
            for (int r = 0; r < 4; r++) {
                int m = m0 + quad * 4 + r;
                if (m < N_NODES) {
                    unsigned pk = (unsigned)(unsigned short)f2bf(acc[0][nt][r])
                                | ((unsigned)(unsigned short)f2bf(acc[1][nt][r]) << 16);
                    *(unsigned*)&Xp[(size_t)m * (C_CH * W_OUTF) + o * 2] = pk;
                }
            }
        }
    } else {
        int bb = bx >> 1;                         // 0..BUILD_TOT-1
        if (bb >= BUILD_TOT) return;
        int t = bb / BUILD_BX;
        int i = (bb - t * BUILD_BX) * 256 + tid;  // oct-edge index
        if (i >= E_EDGE / 8) return;
        int e = i * 8;
        const int*   rbase = &edge_index[(size_t)(t * 2 + 0) * E_EDGE + e];
        const int*   cbase = &edge_index[(size_t)(t * 2 + 1) * E_EDGE + e];
        const float* vbase = &edge_value[(size_t)t * E_EDGE + e];
        int4   r4a = *(const int4*)  &rbase[0], r4b = *(const int4*)  &rbase[4];
        int4   c4a = *(const int4*)  &cbase[0], c4b = *(const int4*)  &cbase[4];
        float4 v4a = *(const float4*)&vbase[0], v4b = *(const float4*)&vbase[4];
        int rows[8] = {r4a.x, r4a.y, r4a.z, r4a.w, r4b.x, r4b.y, r4b.z, r4b.w};
        int cols[8] = {c4a.x, c4a.y, c4a.z, c4a.w, c4b.x, c4b.y, c4b.z, c4b.w};
        float evv[8] = {v4a.x, v4a.y, v4a.z, v4a.w, v4b.x, v4b.y, v4b.z, v4b.w};
        int ids[8];
        #pragma unroll
        for (int j = 0; j < 8; j++) ids[j] = rid[rows[j]];
        #pragma unroll
        for (int j = 0; j < 8; j++) {
            if (ids[j] >= 0) {
                int p = atomicAdd(&counts[ids[j]], 1);
                if (p < MAXDEG) {
                    unsigned long long rec =
                        (unsigned long long)(unsigned)(cols[j] | (t << 20)) |
                        ((unsigned long long)__float_as_uint(evv[j]) << 32);
                    records[(size_t)ids[j] * MAXDEG + p] = rec;
                }
            }
        }
    }
}

// ---------- gather + relu + linear1 + lin head fuse: PERSISTENT WORK QUEUE ----------
// R11 diagnosis: 38% occupancy vs 62% cap = block-retirement imbalance (block
// frees its 32KB LDS slot only when all 4 waves finish their 8 static rows; one
// heavy row strands 3 waves). Fix: exactly 1280 blocks (5/CU residency cap),
// each wave grabs rows from a global atomic queue; next row's 512B record load
// is issued before processing the current row (pipeline across the queue).
// w1s XOR-swizzle proven conflict-free (R9). ~23k atomics total — trivial.
#define GQ_BLOCKS 1280
__device__ __forceinline__ void process_row(
    int n, int cnt, unsigned long long rl, unsigned long long rh,
    const unsigned* __restrict__ xb, const float (*w1s)[W_OUTF],
    const float* f0, const float* f1, float bias, int lane,
    float lw0, float lw1, float lw2, float lw3,
    float lb0, float lb1, float lb2, float lb3,
    float4* __restrict__ yv, int b)
{
    unsigned rl_lo = (unsigned)rl, rl_hi = (unsigned)(rl >> 32);
    unsigned rh_lo = (unsigned)rh, rh_hi = (unsigned)(rh >> 32);
    float a0 = 0.f, a1 = 0.f, a0b = 0.f, a1b = 0.f;
    int nb = (cnt + 15) & ~15;
    for (int p = 0; p < nb; p += 16) {
        // p<64 uniform for the 16-batch (MAXDEG=96 -> p in {0,16,..,80})
        unsigned blo = (p < 64) ? rl_lo : rh_lo;
        unsigned bhi = (p < 64) ? rl_hi : rh_hi;
        int poff = (p < 64) ? p : p - 64;
        unsigned klo[16], khi[16], q[16];
        #pragma unroll
        for (int j = 0; j < 16; j++) {
            klo[j] = __shfl(blo, poff + j);
            khi[j] = __shfl(bhi, poff + j);
        }
        #pragma unroll
        for (int j = 0; j < 16; j++)
            q[j] = xb[(size_t)(klo[j] & 0xFFFFF) * 64];
        #pragma unroll
        for (int j = 0; j < 16; j += 2) {
            int ta = (int)(klo[j] >> 20), tb = (int)(klo[j + 1] >> 20);
            float ea = __uint_as_float(khi[j]), eb = __uint_as_float(khi[j + 1]);
            a0  += ea * f0[ta] * bflo(q[j]);
            a1  += ea * f1[ta] * bfhi(q[j]);
            a0b += eb * f0[tb] * bflo(q[j + 1]);
            a1b += eb * f1[tb] * bfhi(q[j + 1]);
        }
    }
    a0 += a0b; a1 += a1b;
    unsigned qn = xb[(size_t)n * 64];
    float hc0 = fmaxf(BETA * bflo(qn) + (1.f - BETA) * a0, 0.f);
    float hc1 = fmaxf(BETA * bfhi(qn) + (1.f - BETA) * a1, 0.f);
    // in-wave GEMV, 4 partial chains; swizzled column index (k&31 is const)
    float s0 = bias, s1 = 0.f, s2 = 0.f, s3 = 0.f;
    #pragma unroll
    for (int k = 0; k < W_OUTF; k += 4) {
        s0 += __shfl(hc0, k)     * w1s[k][lane ^ (k & 31)];
        s1 += __shfl(hc0, k + 1) * w1s[k + 1][lane ^ ((k + 1) & 31)];
        s2 += __shfl(hc0, k + 2) * w1s[k + 2][lane ^ ((k + 2) & 31)];
        s3 += __shfl(hc0, k + 3) * w1s[k + 3][lane ^ ((k + 3) & 31)];
    }
    #pragma unroll
    for (int k = 0; k < W_OUTF; k += 4) {
        s0 += __shfl(hc1, k)     * w1s[W_OUTF + k][lane ^ (k & 31)];
        s1 += __shfl(hc1, k + 1) * w1s[W_OUTF + k + 1][lane ^ ((k + 1) & 31)];
        s2 += __shfl(hc1, k + 2) * w1s[W_OUTF + k + 2][lane ^ ((k + 2) & 31)];
        s3 += __shfl(hc1, k + 3) * w1s[W_OUTF + k + 3][lane ^ ((k + 3) & 31)];
    }
    float h2 = fmaxf((s0 + s1) + (s2 + s3), 0.f);
    // fused lin head: y_k = sum_lane linW[k][lane]*h2[lane] (+linb)
    float p0 = lw0 * h2, p1 = lw1 * h2, p2 = lw2 * h2, p3 = lw3 * h2;
    #pragma unroll
    for (int off = 32; off > 0; off >>= 1) {
        p0 += __shfl_xor(p0, off);
        p1 += __shfl_xor(p1, off);
        p2 += __shfl_xor(p2, off);
        p3 += __shfl_xor(p3, off);
    }
    if (lane == 0)
        yv[b] = make_float4(p0 + lb0, p1 + lb1, p2 + lb2, p3 + lb3);
}

__global__ __launch_bounds__(256)
void gather_kernel(const int* __restrict__ row_list,
                   const int* __restrict__ counts,
                   const unsigned long long* __restrict__ records,
                   const float* __restrict__ filt,
                   const short* __restrict__ Xp,
                   const float* __restrict__ W1,
                   const float* __restrict__ b1,
                   const float* __restrict__ linW,
                   const float* __restrict__ linb,
                   float4* __restrict__ yv,
                   int* __restrict__ nrows_ptr) {       // [0]=nrows, [1]=work
    __shared__ float w1s[C_CH * W_OUTF][W_OUTF];   // exactly 32 KB, XOR-swizzled
    int tid = threadIdx.x;
    for (int i = tid; i < W_OUTF * C_CH * W_OUTF; i += 256) {
        int o = i >> 7, k = i & 127;
        w1s[k][o ^ (k & 31)] = W1[i];
    }
    __syncthreads();
    int lane = tid & 63;
    int nrows = nrows_ptr[0];
    float f0[T_ET], f1[T_ET];
    #pragma unroll
    for (int t = 0; t < T_ET; t++) { f0[t] = filt[t]; f1[t] = filt[T_ET + t]; }
    float bias = b1[lane];
    float lw0 = linW[0 * W_OUTF + lane], lw1 = linW[1 * W_OUTF + lane];
    float lw2 = linW[2 * W_OUTF + lane], lw3 = linW[3 * W_OUTF + lane];
    float lb0 = linb[0], lb1 = linb[1], lb2 = linb[2], lb3 = linb[3];
    const unsigned* xb = (const unsigned*)Xp + lane;

    // wave-level work queue with 1-row record prefetch
    int cur = 0;
    if (lane == 0) cur = atomicAdd(&nrows_ptr[1], 1);
    cur = __shfl(cur, 0);
    int n_c = 0, c_c = 0;
    unsigned long long rl_c = 0, rh_c = 0;
    if (cur < nrows) {
        n_c = row_list[cur];
        c_c = counts[cur]; if (c_c > MAXDEG) c_c = MAXDEG;
        const unsigned long long* rec = records + (size_t)cur * MAXDEG;
        rl_c = (lane < c_c)      ? rec[lane]      : 0ULL;
        rh_c = (lane + 64 < c_c) ? rec[lane + 64] : 0ULL;
    }
    while (cur < nrows) {
        int nxt = 0;
        if (lane == 0) nxt = atomicAdd(&nrows_ptr[1], 1);
        nxt = __shfl(nxt, 0);
        int n_n = 0, c_n = 0;
        unsigned long long rl_n = 0, rh_n = 0;
        if (nxt < nrows) {                         // issue next row's loads NOW
            n_n = row_list[nxt];
            c_n = counts[nxt]; if (c_n > MAXDEG) c_n = MAXDEG;
            const unsigned long long* rec = records + (size_t)nxt * MAXDEG;
            rl_n = (lane < c_n)      ? rec[lane]      : 0ULL;
            rh_n = (lane + 64 < c_n) ? rec[lane + 64] : 0ULL;
        }
        process_row(n_c, c_c, rl_c, rh_c, xb, w1s, f0, f1, bias, lane,
                    lw0, lw1, lw2, lw3, lb0, lb1, lb2, lb3, yv, cur);
        cur = nxt; n_c = n_n; c_c = c_n; rl_c = rl_n; rh_c = rh_n;
    }
}

// ---------- loss: per-target 16B copy + log-softmax + mean NLL ----------
__global__ void loss_kernel(const float4* __restrict__ yv,
                            const int* __restrict__ rid,
                            const int* __restrict__ target_x,
                            const int* __restrict__ target,
                            float* __restrict__ out) {
    __shared__ float loss_s[4];
    int tid = threadIdx.x;
    int wave = tid >> 6, lane = tid & 63;
    int m = blockIdx.x * 256 + tid;
    float l = 0.f;
    if (m < M_TGT) {
        int id = rid[target_x[m]];
        float4 y = yv[id];
        *(float4*)&out[1 + (size_t)m * NUM_CLS] = y;
        float mx = fmaxf(fmaxf(y.x, y.y), fmaxf(y.z, y.w));
        float s = expf(y.x - mx) + expf(y.y - mx) + expf(y.z - mx) + expf(y.w - mx);
        float lse = mx + logf(s);
        int tg = target[m];
        float ytg = (tg == 0) ? y.x : (tg == 1) ? y.y : (tg == 2) ? y.z : y.w;
        l = lse - ytg;
    }
    #pragma unroll
    for (int off = 32; off > 0; off >>= 1) l += __shfl_xor(l, off);
    if (lane == 0) loss_s[wave] = l;
    __syncthreads();
    if (tid == 0) {
        float L = loss_s[0] + loss_s[1] + loss_s[2] + loss_s[3];
        atomicAdd(&out[0], L * (1.0f / (float)M_TGT));
    }
}

extern "C" void kernel_launch(void* const* d_in, const int* in_sizes, int n_in,
                              void* d_out, int out_size, void* d_ws, size_t ws_size,
                              hipStream_t stream) {
    const float* X           = (const float*)d_in[0];
    const float* edge_value  = (const float*)d_in[1];
    const float* Ws          = (const float*)d_in[2];
    const float* conv_weight = (const float*)d_in[3];
    const float* linear1_W   = (const float*)d_in[4];
    const float* linear1_b   = (const float*)d_in[5];
    const float* lin_W       = (const float*)d_in[6];
    const float* lin_b       = (const float*)d_in[7];
    const int*   edge_index  = (const int*)d_in[8];
    const int*   target_x    = (const int*)d_in[9];
    const int*   target      = (const int*)d_in[10];
    float* out = (float*)d_out;

    char* ws = (char*)d_ws;
    size_t off = 0;
    float* filt  = (float*)(ws + off); off += 256;
    size_t xbytes = (size_t)N_NODES * C_CH * W_OUTF * sizeof(short);  // 25.6 MB bf16
    short* Xp    = (short*)(ws + off); off += xbytes;
    float4* yv   = (float4*)(ws + off); off += (size_t)M_TGT * sizeof(float4); // 320 KB
    unsigned long long* records = (unsigned long long*)(ws + off);
    off += (size_t)M_TGT * MAXDEG * sizeof(unsigned long long);       // 15.4 MB
    short* Bt    = (short*)(ws + off); off += (size_t)C_CH * W_OUTF * W_INF * sizeof(short);
    int*   rid   = (int*)  (ws + off); off += (size_t)N_NODES * sizeof(int);
    int*   row_list = (int*)(ws + off); off += (size_t)M_TGT * sizeof(int);
    int*   counts   = (int*)(ws + off); off += (size_t)M_TGT * sizeof(int);
    int*   nrows    = (int*)(ws + off); off += 256;

    hipMemsetAsync(rid, 0xFF, (size_t)N_NODES * sizeof(int), stream);   // -1

    setup_kernel<<<128, 256, 0, stream>>>(Ws, conv_weight, target_x, Bt, filt, rid, nrows, out);
    compact_kernel<<<(N_NODES + 255) / 256, 256, 0, stream>>>(rid, row_list, nrows, counts);
    fused_gemm_build<<<2 * BUILD_TOT, 256, 0, stream>>>(
        X, Bt, Xp, edge_index, edge_value, rid, counts, records);
    gather_kernel<<<GQ_BLOCKS, 256, 0, stream>>>(
        row_list, counts, records, filt, Xp, linear1_W, linear1_b,
        lin_W, lin_b, yv, nrows);
    loss_kernel<<<(M_TGT + 255) / 256, 256, 0, stream>>>(yv, rid, target_x, target, out);
}

// Round 13
// 283.665 us; speedup vs baseline: 1.8030x; 1.8030x over previous
//
#include <hip/hip_runtime.h>

#define N_NODES 100000
#define W_INF   256
#define W_OUTF  64
#define C_CH    2
#define T_ET    4
#define E_EDGE  800000
#define NUM_CLS 4
#define M_TGT   20000
#define BETA    0.5f
#define MAXDEG  96

typedef __attribute__((ext_vector_type(8))) short bf16x8;
typedef __attribute__((ext_vector_type(4))) float floatx4;

__device__ inline short f2bf(float f) {
    unsigned u = __builtin_bit_cast(unsigned, f);
    u += 0x7FFF + ((u >> 16) & 1);          // RNE
    return (short)(u >> 16);
}
// packed dword q = (bf16 lo) | (bf16 hi << 16)
__device__ inline float bflo(unsigned q) { return __builtin_bit_cast(float, q << 16); }
__device__ inline float bfhi(unsigned q) { return __builtin_bit_cast(float, q & 0xFFFF0000u); }
// compile-time-constant lane broadcast (VALU readlane, no DS pipe)
__device__ __forceinline__ float rlane(float v, int k) {
    return __builtin_bit_cast(float,
        __builtin_amdgcn_readlane(__builtin_bit_cast(int, v), k));
}

// ---------- setup: softmax(filt) + Bt convert + mark rid + zero scalars ----------
__global__ void setup_kernel(const float* __restrict__ Ws,
                             const float* __restrict__ conv_weight,
                             const int* __restrict__ target_x,
                             short* __restrict__ Bt, float* __restrict__ filt,
                             int* __restrict__ rid, int* __restrict__ nrows,
                             float* __restrict__ out) {
    int i = blockIdx.x * 256 + threadIdx.x;
    if (i == 0) { nrows[0] = 0; out[0] = 0.f; }
    if (i < C_CH) {
        int c = i;
        float mx = -1e30f;
        for (int t = 0; t < T_ET; t++) mx = fmaxf(mx, conv_weight[c * T_ET + t]);
        float e[T_ET];
        float s = 0.f;
        for (int t = 0; t < T_ET; t++) { e[t] = expf(conv_weight[c * T_ET + t] - mx); s += e[t]; }
        for (int t = 0; t < T_ET; t++) filt[c * T_ET + t] = e[t] / s;
    }
    if (i < C_CH * W_OUTF * W_INF) {
        int co = i >> 8, k = i & 255;
        int c = co >> 6, o = co & 63;
        Bt[i] = f2bf(Ws[((size_t)c * W_INF + k) * W_OUTF + o]);
    }
    if (i < M_TGT) rid[target_x[i]] = -2;
}

// ---------- compact flagged rows (wave-aggregated atomic) + zero counts ----------
__global__ void compact_kernel(int* __restrict__ rid, int* __restrict__ row_list,
                               int* __restrict__ nrows, int* __restrict__ counts) {
    int n = blockIdx.x * blockDim.x + threadIdx.x;
    if (n < M_TGT) counts[n] = 0;          // consumed by fused build (next dispatch)
    int lane = threadIdx.x & 63;
    bool flag = (n < N_NODES) && (rid[n] == -2);
    unsigned long long mask = __ballot(flag);
    int base = 0;
    if (lane == 0 && mask) base = atomicAdd(nrows, __popcll(mask));
    base = __shfl(base, 0);
    if (flag) {
        int id = base + __popcll(mask & ((1ULL << lane) - 1ULL));
        rid[n] = id;
        row_list[id] = n;
    }
}

// ---------- fused: MFMA gemm (even blocks) + edge binning (odd blocks) ----------
// gemm: EXACT R9 config — proven ~73us local floor (5 experiments bracket it).
// build: NOW FOLDS filt INTO THE RECORD — t is block-uniform, so
// ef0 = e*filt[0][t]*(1-B), ef1 = e*filt[1][t]*(1-B) are packed as 2xbf16 in
// the record's high dword (col in low 20 bits). Gather's per-edge cost halves
// (no runtime f[t] cndmask chains, no mul by f). Record stays 8 bytes.
#define GMT  64
#define BLDA2 136
#define GEMM_NB  ((N_NODES + GMT - 1) / GMT)      // 1563
#define BUILD_BX ((E_EDGE / 8 + 255) / 256)       // 391
#define BUILD_TOT (BUILD_BX * T_ET)               // 1564
__global__ __launch_bounds__(256, 4)
void fused_gemm_build(const float* __restrict__ X, const short* __restrict__ Bt,
                      short* __restrict__ Xp,
                      const int* __restrict__ edge_index,
                      const float* __restrict__ edge_value,
                      const float* __restrict__ filt,
                      const int* __restrict__ rid,
                      int* __restrict__ counts,
                      unsigned long long* __restrict__ records) {
    __shared__ short Bl[64][BLDA2];    // 17.4 KB: 64 output-rows x 128 k per stage
    int tid = threadIdx.x;
    int bx = blockIdx.x;
    if ((bx & 1) == 0) {
        int g = bx >> 1;
        if (g >= GEMM_NB) return;
        int w = tid >> 6, lane = tid & 63;
        int quad = lane >> 4, l15 = lane & 15;
        int m0 = g * GMT + w * 16;
        int arow = m0 + l15;
        if (arow >= N_NODES) arow = N_NODES - 1;
        const float* xrow = X + (size_t)arow * W_INF;
        floatx4 acc[C_CH][4] = {};
        #pragma unroll 1
        for (int kh = 0; kh < 2; kh++) {          // K-half: addresses only
            // A strip for this K-half: 4 chunks x 8 bf16 = 16 VGPRs
            bf16x8 af[4];
            #pragma unroll
            for (int kc = 0; kc < 4; kc++) {
                int kb = kh * 128 + kc * 32 + quad * 8;
                float4 v0 = *(const float4*)&xrow[kb];
                float4 v1 = *(const float4*)&xrow[kb + 4];
                af[kc][0] = f2bf(v0.x); af[kc][1] = f2bf(v0.y);
                af[kc][2] = f2bf(v0.z); af[kc][3] = f2bf(v0.w);
                af[kc][4] = f2bf(v1.x); af[kc][5] = f2bf(v1.y);
                af[kc][6] = f2bf(v1.z); af[kc][7] = f2bf(v1.w);
            }
            #pragma unroll
            for (int c = 0; c < C_CH; c++) {      // fully unrolled: acc static
                if (kh | c) __syncthreads();      // protect re-stage
                // stage channel c, K-half kh: 64 rows x 128 k (1024 x 16B chunks)
                #pragma unroll
                for (int l = 0; l < 4; l++) {
                    int idx = tid + l * 256;
                    int r = idx >> 4;
                    int kp = (idx & 15) * 8;
                    *(bf16x8*)&Bl[r][kp] =
                        *(const bf16x8*)&Bt[(size_t)(c * 64 + r) * W_INF + kh * 128 + kp];
                }
                __syncthreads();
                #pragma unroll
                for (int kc = 0; kc < 4; kc++) {
                    int kb = kc * 32 + quad * 8;
                    #pragma unroll
                    for (int nt = 0; nt < 4; nt++) {
                        bf16x8 b = *(bf16x8*)&Bl[nt * 16 + l15][kb];
                        acc[c][nt] =
                            __builtin_amdgcn_mfma_f32_16x16x32_bf16(af[kc], b, acc[c][nt], 0, 0, 0);
                    }
                }
            }
        }
        // D layout: o = nt*16 + l15; m = m0 + quad*4 + r. Pack both channels.
        #pragma unroll
        for (int nt = 0; nt < 4; nt++) {
            int o = nt * 16 + l15;
            #pragma unroll
            for (int r = 0; r < 4; r++) {
                int m = m0 + quad * 4 + r;
                if (m < N_NODES) {
                    unsigned pk = (unsigned)(unsigned short)f2bf(acc[0][nt][r])
                                | ((unsigned)(unsigned short)f2bf(acc[1][nt][r]) << 16);
                    *(unsigned*)&Xp[(size_t)m * (C_CH * W_OUTF) + o * 2] = pk;
                }
            }
        }
    } else {
        int bb = bx >> 1;                         // 0..BUILD_TOT-1
        if (bb >= BUILD_TOT) return;
        int t = bb / BUILD_BX;
        int i = (bb - t * BUILD_BX) * 256 + tid;  // oct-edge index
        if (i >= E_EDGE / 8) return;
        // block-uniform filter factors, pre-scaled by (1-BETA)
        float f0t = filt[t] * (1.0f - BETA);
        float f1t = filt[T_ET + t] * (1.0f - BETA);
        int e = i * 8;
        const int*   rbase = &edge_index[(size_t)(t * 2 + 0) * E_EDGE + e];
        const int*   cbase = &edge_index[(size_t)(t * 2 + 1) * E_EDGE + e];
        const float* vbase = &edge_value[(size_t)t * E_EDGE + e];
        int4   r4a = *(const int4*)  &rbase[0], r4b = *(const int4*)  &rbase[4];
        int4   c4a = *(const int4*)  &cbase[0], c4b = *(const int4*)  &cbase[4];
        float4 v4a = *(const float4*)&vbase[0], v4b = *(const float4*)&vbase[4];
        int rows[8] = {r4a.x, r4a.y, r4a.z, r4a.w, r4b.x, r4b.y, r4b.z, r4b.w};
        int cols[8] = {c4a.x, c4a.y, c4a.z, c4a.w, c4b.x, c4b.y, c4b.z, c4b.w};
        float evv[8] = {v4a.x, v4a.y, v4a.z, v4a.w, v4b.x, v4b.y, v4b.z, v4b.w};
        int ids[8];
        #pragma unroll
        for (int j = 0; j < 8; j++) ids[j] = rid[rows[j]];
        #pragma unroll
        for (int j = 0; j < 8; j++) {
            if (ids[j] >= 0) {
                int p = atomicAdd(&counts[ids[j]], 1);
                if (p < MAXDEG) {
                    unsigned ef = (unsigned)(unsigned short)f2bf(evv[j] * f0t)
                                | ((unsigned)(unsigned short)f2bf(evv[j] * f1t) << 16);
                    unsigned long long rec =
                        (unsigned long long)(unsigned)cols[j] |
                        ((unsigned long long)ef << 32);
                    records[(size_t)ids[j] * MAXDEG + p] = rec;
                }
            }
        }
    }
}

// ---------- gather + relu + linear1 + lin head fuse (R11 static structure) ----------
// R12 lesson: persistent queue tripled VGPR (168) -> 11% occupancy, 3.3x slower.
// Back to the PROVEN static 2-row pipeline (R11: 82us, VGPR 60). New in R13:
//  - records carry pre-scaled bf16 {ef0,ef1}: per-edge = 4 bit-ops + 2 fma
//    (was ~14 VALU incl. runtime-f[t] cndmask chains).
//  - GEMV broadcast via readlane (compile-const k): VALU op, frees DS pipe
//    (was 128 ds_bpermute/row contending with w1s ds_reads).
#define GROWS 8
__device__ __forceinline__ void process_row(
    int n, int cnt, unsigned long long rl, unsigned long long rh,
    const unsigned* __restrict__ xb, const float (*w1s)[W_OUTF],
    float bias, int lane,
    float lw0, float lw1, float lw2, float lw3,
    float lb0, float lb1, float lb2, float lb3,
    float4* __restrict__ yv, int b)
{
    unsigned rl_lo = (unsigned)rl, rl_hi = (unsigned)(rl >> 32);
    unsigned rh_lo = (unsigned)rh, rh_hi = (unsigned)(rh >> 32);
    float a0 = 0.f, a1 = 0.f, a0b = 0.f, a1b = 0.f;
    int nb = (cnt + 15) & ~15;
    for (int p = 0; p < nb; p += 16) {
        // p<64 uniform for the 16-batch (MAXDEG=96 -> p in {0,16,..,80})
        unsigned blo = (p < 64) ? rl_lo : rh_lo;
        unsigned bhi = (p < 64) ? rl_hi : rh_hi;
        int poff = (p < 64) ? p : p - 64;
        unsigned klo[16], khi[16], q[16];
        #pragma unroll
        for (int j = 0; j < 16; j++) {
            klo[j] = __shfl(blo, poff + j);
            khi[j] = __shfl(bhi, poff + j);
        }
        #pragma unroll
        for (int j = 0; j < 16; j++)
            q[j] = xb[(size_t)(klo[j] & 0xFFFFF) * 64];
        #pragma unroll
        for (int j = 0; j < 16; j += 2) {
            a0  += bflo(khi[j])     * bflo(q[j]);
            a1  += bfhi(khi[j])     * bfhi(q[j]);
            a0b += bflo(khi[j + 1]) * bflo(q[j + 1]);
            a1b += bfhi(khi[j + 1]) * bfhi(q[j + 1]);
        }
    }
    a0 += a0b; a1 += a1b;
    unsigned qn = xb[(size_t)n * 64];
    float hc0 = fmaxf(BETA * bflo(qn) + a0, 0.f);   // (1-B) pre-folded into ef
    float hc1 = fmaxf(BETA * bfhi(qn) + a1, 0.f);
    // in-wave GEMV, 4 partial chains; readlane broadcast; swizzled columns
    float s0 = bias, s1 = 0.f, s2 = 0.f, s3 = 0.f;
    #pragma unroll
    for (int k = 0; k < W_OUTF; k += 4) {
        s0 += rlane(hc0, k)     * w1s[k][lane ^ (k & 31)];
        s1 += rlane(hc0, k + 1) * w1s[k + 1][lane ^ ((k + 1) & 31)];
        s2 += rlane(hc0, k + 2) * w1s[k + 2][lane ^ ((k + 2) & 31)];
        s3 += rlane(hc0, k + 3) * w1s[k + 3][lane ^ ((k + 3) & 31)];
    }
    #pragma unroll
    for (int k = 0; k < W_OUTF; k += 4) {
        s0 += rlane(hc1, k)     * w1s[W_OUTF + k][lane ^ (k & 31)];
        s1 += rlane(hc1, k + 1) * w1s[W_OUTF + k + 1][lane ^ ((k + 1) & 31)];
        s2 += rlane(hc1, k + 2) * w1s[W_OUTF + k + 2][lane ^ ((k + 2) & 31)];
        s3 += rlane(hc1, k + 3) * w1s[W_OUTF + k + 3][lane ^ ((k + 3) & 31)];
    }
    float h2 = fmaxf((s0 + s1) + (s2 + s3), 0.f);
    // fused lin head: y_k = sum_lane linW[k][lane]*h2[lane] (+linb)
    float p0 = lw0 * h2, p1 = lw1 * h2, p2 = lw2 * h2, p3 = lw3 * h2;
    #pragma unroll
    for (int off = 32; off > 0; off >>= 1) {
        p0 += __shfl_xor(p0, off);
        p1 += __shfl_xor(p1, off);
        p2 += __shfl_xor(p2, off);
        p3 += __shfl_xor(p3, off);
    }
    if (lane == 0)
        yv[b] = make_float4(p0 + lb0, p1 + lb1, p2 + lb2, p3 + lb3);
}

__global__ void gather_kernel(const int* __restrict__ row_list,
                              const int* __restrict__ counts,
                              const unsigned long long* __restrict__ records,
                              const short* __restrict__ Xp,
                              const float* __restrict__ W1,
                              const float* __restrict__ b1,
                              const float* __restrict__ linW,
                              const float* __restrict__ linb,
                              float4* __restrict__ yv,
                              const int* __restrict__ nrows_ptr) {
    __shared__ float w1s[C_CH * W_OUTF][W_OUTF];   // exactly 32 KB, XOR-swizzled
    int tid = threadIdx.x;
    for (int i = tid; i < W_OUTF * C_CH * W_OUTF; i += 256) {
        int o = i >> 7, k = i & 127;
        w1s[k][o ^ (k & 31)] = W1[i];
    }
    __syncthreads();
    int w = tid >> 6, lane = tid & 63;
    int nrows = nrows_ptr[0];
    float bias = b1[lane];
    float lw0 = linW[0 * W_OUTF + lane], lw1 = linW[1 * W_OUTF + lane];
    float lw2 = linW[2 * W_OUTF + lane], lw3 = linW[3 * W_OUTF + lane];
    float lb0 = linb[0], lb1 = linb[1], lb2 = linb[2], lb3 = linb[3];
    const unsigned* xb = (const unsigned*)Xp + lane;

    int b0 = blockIdx.x * GROWS + w;
    int b1r = b0 + 4;
    bool v0 = b0 < nrows, v1 = b1r < nrows;
    int n0 = 0, c0 = 0, n1 = 0, c1 = 0;
    unsigned long long rl0 = 0, rh0 = 0, rl1 = 0, rh1 = 0;
    if (v0) {
        n0 = row_list[b0];
        c0 = counts[b0]; if (c0 > MAXDEG) c0 = MAXDEG;
        const unsigned long long* rec = records + (size_t)b0 * MAXDEG;
        rl0 = (lane < c0)      ? rec[lane]      : 0ULL;
        rh0 = (lane + 64 < c0) ? rec[lane + 64] : 0ULL;
    }
    if (v1) {
        n1 = row_list[b1r];
        c1 = counts[b1r]; if (c1 > MAXDEG) c1 = MAXDEG;
        const unsigned long long* rec = records + (size_t)b1r * MAXDEG;
        rl1 = (lane < c1)      ? rec[lane]      : 0ULL;
        rh1 = (lane + 64 < c1) ? rec[lane + 64] : 0ULL;
    }
    if (v0) process_row(n0, c0, rl0, rh0, xb, w1s, bias, lane,
                        lw0, lw1, lw2, lw3, lb0, lb1, lb2, lb3, yv, b0);
    if (v1) process_row(n1, c1, rl1, rh1, xb, w1s, bias, lane,
                        lw0, lw1, lw2, lw3, lb0, lb1, lb2, lb3, yv, b1r);
}

// ---------- loss: per-target 16B copy + log-softmax + mean NLL ----------
__global__ void loss_kernel(const float4* __restrict__ yv,
                            const int* __restrict__ rid,
                            const int* __restrict__ target_x,
                            const int* __restrict__ target,
                            float* __restrict__ out) {
    __shared__ float loss_s[4];
    int tid = threadIdx.x;
    int wave = tid >> 6, lane = tid & 63;
    int m = blockIdx.x * 256 + tid;
    float l = 0.f;
    if (m < M_TGT) {
        int id = rid[target_x[m]];
        float4 y = yv[id];
        *(float4*)&out[1 + (size_t)m * NUM_CLS] = y;
        float mx = fmaxf(fmaxf(y.x, y.y), fmaxf(y.z, y.w));
        float s = expf(y.x - mx) + expf(y.y - mx) + expf(y.z - mx) + expf(y.w - mx);
        float lse = mx + logf(s);
        int tg = target[m];
        float ytg = (tg == 0) ? y.x : (tg == 1) ? y.y : (tg == 2) ? y.z : y.w;
        l = lse - ytg;
    }
    #pragma unroll
    for (int off = 32; off > 0; off >>= 1) l += __shfl_xor(l, off);
    if (lane == 0) loss_s[wave] = l;
    __syncthreads();
    if (tid == 0) {
        float L = loss_s[0] + loss_s[1] + loss_s[2] + loss_s[3];
        atomicAdd(&out[0], L * (1.0f / (float)M_TGT));
    }
}

extern "C" void kernel_launch(void* const* d_in, const int* in_sizes, int n_in,
                              void* d_out, int out_size, void* d_ws, size_t ws_size,
                              hipStream_t stream) {
    const float* X           = (const float*)d_in[0];
    const float* edge_value  = (const float*)d_in[1];
    const float* Ws          = (const float*)d_in[2];
    const float* conv_weight = (const float*)d_in[3];
    const float* linear1_W   = (const float*)d_in[4];
    const float* linear1_b   = (const float*)d_in[5];
    const float* lin_W       = (const float*)d_in[6];
    const float* lin_b       = (const float*)d_in[7];
    const int*   edge_index  = (const int*)d_in[8];
    const int*   target_x    = (const int*)d_in[9];
    const int*   target      = (const int*)d_in[10];
    float* out = (float*)d_out;

    char* ws = (char*)d_ws;
    size_t off = 0;
    float* filt  = (float*)(ws + off); off += 256;
    size_t xbytes = (size_t)N_NODES * C_CH * W_OUTF * sizeof(short);  // 25.6 MB bf16
    short* Xp    = (short*)(ws + off); off += xbytes;
    float4* yv   = (float4*)(ws + off); off += (size_t)M_TGT * sizeof(float4); // 320 KB
    unsigned long long* records = (unsigned long long*)(ws + off);
    off += (size_t)M_TGT * MAXDEG * sizeof(unsigned long long);       // 15.4 MB
    short* Bt    = (short*)(ws + off); off += (size_t)C_CH * W_OUTF * W_INF * sizeof(short);
    int*   rid   = (int*)  (ws + off); off += (size_t)N_NODES * sizeof(int);
    int*   row_list = (int*)(ws + off); off += (size_t)M_TGT * sizeof(int);
    int*   counts   = (int*)(ws + off); off += (size_t)M_TGT * sizeof(int);
    int*   nrows    = (int*)(ws + off); off += 256;

    hipMemsetAsync(rid, 0xFF, (size_t)N_NODES * sizeof(int), stream);   // -1

    setup_kernel<<<128, 256, 0, stream>>>(Ws, conv_weight, target_x, Bt, filt, rid, nrows, out);
    compact_kernel<<<(N_NODES + 255) / 256, 256, 0, stream>>>(rid, row_list, nrows, counts);
    fused_gemm_build<<<2 * BUILD_TOT, 256, 0, stream>>>(
        X, Bt, Xp, edge_index, edge_value, filt, rid, counts, records);
    gather_kernel<<<(M_TGT + GROWS - 1) / GROWS, 256, 0, stream>>>(
        row_list, counts, records, Xp, linear1_W, linear1_b,
        lin_W, lin_b, yv, nrows);
    loss_kernel<<<(M_TGT + 255) / 256, 256, 0, stream>>>(yv, rid, target_x, target, out);
}

// Round 14
// 278.284 us; speedup vs baseline: 1.8379x; 1.0193x over previous
//
#include <hip/hip_runtime.h>

#define N_NODES 100000
#define W_INF   256
#define W_OUTF  64
#define C_CH    2
#define T_ET    4
#define E_EDGE  800000
#define NUM_CLS 4
#define M_TGT   20000
#define BETA    0.5f
#define MAXDEG  96

typedef __attribute__((ext_vector_type(8))) short bf16x8;
typedef __attribute__((ext_vector_type(4))) float floatx4;
typedef unsigned long long ull;

__device__ inline short f2bf(float f) {
    unsigned u = __builtin_bit_cast(unsigned, f);
    u += 0x7FFF + ((u >> 16) & 1);          // RNE
    return (short)(u >> 16);
}
// packed dword q = (bf16 lo) | (bf16 hi << 16)
__device__ inline float bflo(unsigned q) { return __builtin_bit_cast(float, q << 16); }
__device__ inline float bfhi(unsigned q) { return __builtin_bit_cast(float, q & 0xFFFF0000u); }
// fp32 -> bf16 hi (truncate) + bf16 lo (RNE of residual): hi+lo ~ 2^-16 rel
__device__ inline void bfsplit(float v, short& h, short& l) {
    unsigned u = __builtin_bit_cast(unsigned, v) & 0xFFFF0000u;
    h = (short)(u >> 16);
    l = f2bf(v - __builtin_bit_cast(float, u));
}

// ---------- setup: softmax(filt) + Bt convert + W1 hi/lo split + mark rid ----------
__global__ void setup_kernel(const float* __restrict__ Ws,
                             const float* __restrict__ conv_weight,
                             const float* __restrict__ W1,
                             const int* __restrict__ target_x,
                             short* __restrict__ Bt,
                             short* __restrict__ w1h, short* __restrict__ w1l,
                             float* __restrict__ filt,
                             int* __restrict__ rid, int* __restrict__ nrows,
                             float* __restrict__ out) {
    int i = blockIdx.x * 256 + threadIdx.x;
    if (i == 0) { nrows[0] = 0; out[0] = 0.f; }
    if (i < C_CH) {
        int c = i;
        float mx = -1e30f;
        for (int t = 0; t < T_ET; t++) mx = fmaxf(mx, conv_weight[c * T_ET + t]);
        float e[T_ET];
        float s = 0.f;
        for (int t = 0; t < T_ET; t++) { e[t] = expf(conv_weight[c * T_ET + t] - mx); s += e[t]; }
        for (int t = 0; t < T_ET; t++) filt[c * T_ET + t] = e[t] / s;
    }
    if (i < C_CH * W_OUTF * W_INF) {
        int co = i >> 8, k = i & 255;
        int c = co >> 6, o = co & 63;
        Bt[i] = f2bf(Ws[((size_t)c * W_INF + k) * W_OUTF + o]);
    }
    if (i < C_CH * W_OUTF * W_OUTF) {       // 8192: W1 [o=64][k=128] hi/lo split
        short h, l;
        bfsplit(W1[i], h, l);
        w1h[i] = h; w1l[i] = l;
    }
    if (i < M_TGT) rid[target_x[i]] = -2;
}

// ---------- compact flagged rows (wave-aggregated atomic) + zero counts ----------
__global__ void compact_kernel(int* __restrict__ rid, int* __restrict__ row_list,
                               int* __restrict__ nrows, int* __restrict__ counts) {
    int n = blockIdx.x * blockDim.x + threadIdx.x;
    if (n < M_TGT) counts[n] = 0;          // consumed by fused build (next dispatch)
    int lane = threadIdx.x & 63;
    bool flag = (n < N_NODES) && (rid[n] == -2);
    unsigned long long mask = __ballot(flag);
    int base = 0;
    if (lane == 0 && mask) base = atomicAdd(nrows, __popcll(mask));
    base = __shfl(base, 0);
    if (flag) {
        int id = base + __popcll(mask & ((1ULL << lane) - 1ULL));
        rid[n] = id;
        row_list[id] = n;
    }
}

// ---------- fused: MFMA gemm (even blocks) + edge binning (odd blocks) ----------
// gemm: R9 structure (proven ~73us floor). BLDA2 136->152: stride 76 dw == 12
// mod 32 -> bank = 4*(3*l15+quad) mod 32, 3*l15+q bijective mod 8 -> minimal
// conflicts on the b128 reads (was 4(l15+quad): ~1.6M extra cycles).
// build: folds filt*(1-B) into record as packed bf16 {ef0,ef1} (R13, proven).
#define GMT  64
#define BLDA2 152
#define GEMM_NB  ((N_NODES + GMT - 1) / GMT)      // 1563
#define BUILD_BX ((E_EDGE / 8 + 255) / 256)       // 391
#define BUILD_TOT (BUILD_BX * T_ET)               // 1564
__global__ __launch_bounds__(256, 4)
void fused_gemm_build(const float* __restrict__ X, const short* __restrict__ Bt,
                      short* __restrict__ Xp,
                      const int* __restrict__ edge_index,
                      const float* __restrict__ edge_value,
                      const float* __restrict__ filt,
                      const int* __restrict__ rid,
                      int* __restrict__ counts,
                      unsigned long long* __restrict__ records) {
    __shared__ short Bl[64][BLDA2];    // 19.5 KB: 64 output-rows x 128 k per stage
    int tid = threadIdx.x;
    int bx = blockIdx.x;
    if ((bx & 1) == 0) {
        int g = bx >> 1;
        if (g >= GEMM_NB) return;
        int w = tid >> 6, lane = tid & 63;
        int quad = lane >> 4, l15 = lane & 15;
        int m0 = g * GMT + w * 16;
        int arow = m0 + l15;
        if (arow >= N_NODES) arow = N_NODES - 1;
        const float* xrow = X + (size_t)arow * W_INF;
        floatx4 acc[C_CH][4] = {};
        #pragma unroll 1
        for (int kh = 0; kh < 2; kh++) {          // K-half: addresses only
            bf16x8 af[4];
            #pragma unroll
            for (int kc = 0; kc < 4; kc++) {
                int kb = kh * 128 + kc * 32 + quad * 8;
                float4 v0 = *(const float4*)&xrow[kb];
                float4 v1 = *(const float4*)&xrow[kb + 4];
                af[kc][0] = f2bf(v0.x); af[kc][1] = f2bf(v0.y);
                af[kc][2] = f2bf(v0.z); af[kc][3] = f2bf(v0.w);
                af[kc][4] = f2bf(v1.x); af[kc][5] = f2bf(v1.y);
                af[kc][6] = f2bf(v1.z); af[kc][7] = f2bf(v1.w);
            }
            #pragma unroll
            for (int c = 0; c < C_CH; c++) {      // fully unrolled: acc static
                if (kh | c) __syncthreads();      // protect re-stage
                #pragma unroll
                for (int l = 0; l < 4; l++) {
                    int idx = tid + l * 256;
                    int r = idx >> 4;
                    int kp = (idx & 15) * 8;
                    *(bf16x8*)&Bl[r][kp] =
                        *(const bf16x8*)&Bt[(size_t)(c * 64 + r) * W_INF + kh * 128 + kp];
                }
                __syncthreads();
                #pragma unroll
                for (int kc = 0; kc < 4; kc++) {
                    int kb = kc * 32 + quad * 8;
                    #pragma unroll
                    for (int nt = 0; nt < 4; nt++) {
                        bf16x8 b = *(bf16x8*)&Bl[nt * 16 + l15][kb];
                        acc[c][nt] =
                            __builtin_amdgcn_mfma_f32_16x16x32_bf16(af[kc], b, acc[c][nt], 0, 0, 0);
                    }
                }
            }
        }
        #pragma unroll
        for (int nt = 0; nt < 4; nt++) {
            int o = nt * 16 + l15;
            #pragma unroll
            for (int r = 0; r < 4; r++) {
                int m = m0 + quad * 4 + r;
                if (m < N_NODES) {
                    unsigned pk = (unsigned)(unsigned short)f2bf(acc[0][nt][r])
                                | ((unsigned)(unsigned short)f2bf(acc[1][nt][r]) << 16);
                    *(unsigned*)&Xp[(size_t)m * (C_CH * W_OUTF) + o * 2] = pk;
                }
            }
        }
    } else {
        int bb = bx >> 1;                         // 0..BUILD_TOT-1
        if (bb >= BUILD_TOT) return;
        int t = bb / BUILD_BX;
        int i = (bb - t * BUILD_BX) * 256 + tid;  // oct-edge index
        if (i >= E_EDGE / 8) return;
        float f0t = filt[t] * (1.0f - BETA);
        float f1t = filt[T_ET + t] * (1.0f - BETA);
        int e = i * 8;
        const int*   rbase = &edge_index[(size_t)(t * 2 + 0) * E_EDGE + e];
        const int*   cbase = &edge_index[(size_t)(t * 2 + 1) * E_EDGE + e];
        const float* vbase = &edge_value[(size_t)t * E_EDGE + e];
        int4   r4a = *(const int4*)  &rbase[0], r4b = *(const int4*)  &rbase[4];
        int4   c4a = *(const int4*)  &cbase[0], c4b = *(const int4*)  &cbase[4];
        float4 v4a = *(const float4*)&vbase[0], v4b = *(const float4*)&vbase[4];
        int rows[8] = {r4a.x, r4a.y, r4a.z, r4a.w, r4b.x, r4b.y, r4b.z, r4b.w};
        int cols[8] = {c4a.x, c4a.y, c4a.z, c4a.w, c4b.x, c4b.y, c4b.z, c4b.w};
        float evv[8] = {v4a.x, v4a.y, v4a.z, v4a.w, v4b.x, v4b.y, v4b.z, v4b.w};
        int ids[8];
        #pragma unroll
        for (int j = 0; j < 8; j++) ids[j] = rid[rows[j]];
        #pragma unroll
        for (int j = 0; j < 8; j++) {
            if (ids[j] >= 0) {
                int p = atomicAdd(&counts[ids[j]], 1);
                if (p < MAXDEG) {
                    unsigned ef = (unsigned)(unsigned short)f2bf(evv[j] * f0t)
                                | ((unsigned)(unsigned short)f2bf(evv[j] * f1t) << 16);
                    unsigned long long rec =
                        (unsigned long long)(unsigned)cols[j] |
                        ((unsigned long long)ef << 32);
                    records[(size_t)ids[j] * MAXDEG + p] = rec;
                }
            }
        }
    }
}

// ---------- gather: edge-loop per wave -> hcat to LDS (bf16 hi/lo) -> MFMA GEMV ----------
// R13 GEMV cost model: 128 ds_read_b32 + 128 readlane + 128 fma per row x 18.4k
// rows = 2.36M ds ops ~ 22us of LDS pipe. Replaced by 48 MFMA per 16 rows
// (split-bf16: AhiBhi + AloBhi + AhiBlo keeps fp32-class accuracy -> absmax
// unchanged). W1 hi/lo pre-split in setup, fragments read from global (L2-hot,
// 96 reads/block, latency hidden by other waves' edge phase — NOT R10's
// per-K-step hot loop). No w1s LDS: 32KB -> ~10KB, no per-block W1 staging.
#define GROWS2 16
__global__ __launch_bounds__(256)
void gather_kernel(const int* __restrict__ row_list,
                   const int* __restrict__ counts,
                   const unsigned long long* __restrict__ records,
                   const short* __restrict__ Xp,
                   const short* __restrict__ w1h, const short* __restrict__ w1l,
                   const float* __restrict__ b1,
                   const float* __restrict__ linW,
                   const float* __restrict__ linb,
                   float4* __restrict__ yv,
                   const int* __restrict__ nrows_ptr) {
    __shared__ short hcH[GROWS2][136];     // 4.35 KB  (136*2B = 272B row, 16B-aligned)
    __shared__ short hcL[GROWS2][136];     // 4.35 KB
    __shared__ float linS[NUM_CLS][W_OUTF];
    int tid = threadIdx.x;
    int nrows = nrows_ptr[0];
    int blockStart = blockIdx.x * GROWS2;
    if (blockStart >= nrows) return;
    if (tid < NUM_CLS * W_OUTF) linS[tid >> 6][tid & 63] = linW[tid];
    int w = tid >> 6, lane = tid & 63;
    const unsigned* xb = (const unsigned*)Xp + lane;

    // ---- phase A: each wave edge-gathers 4 rows; all 4 rows' records upfront ----
    int base = blockStart + w * 4;
    int nn[4], cc[4];
    ull rl[4], rh[4];
    #pragma unroll
    for (int r = 0; r < 4; r++) {
        int b = base + r;
        nn[r] = 0; cc[r] = 0; rl[r] = 0; rh[r] = 0;
        if (b < nrows) {
            nn[r] = row_list[b];
            int c = counts[b]; if (c > MAXDEG) c = MAXDEG;
            cc[r] = c;
            const ull* rec = records + (size_t)b * MAXDEG;
            rl[r] = (lane < c)      ? rec[lane]      : 0ULL;
            rh[r] = (lane + 64 < c) ? rec[lane + 64] : 0ULL;
        }
    }
    #pragma unroll
    for (int r = 0; r < 4; r++) {
        if (base + r < nrows) {
            unsigned rl_lo = (unsigned)rl[r], rl_hi = (unsigned)(rl[r] >> 32);
            unsigned rh_lo = (unsigned)rh[r], rh_hi = (unsigned)(rh[r] >> 32);
            float a0 = 0.f, a1 = 0.f, a0b = 0.f, a1b = 0.f;
            int nb = (cc[r] + 15) & ~15;
            for (int p = 0; p < nb; p += 16) {
                unsigned blo = (p < 64) ? rl_lo : rh_lo;
                unsigned bhi = (p < 64) ? rl_hi : rh_hi;
                int poff = (p < 64) ? p : p - 64;
                unsigned klo[16], khi[16], q[16];
                #pragma unroll
                for (int j = 0; j < 16; j++) {
                    klo[j] = __shfl(blo, poff + j);
                    khi[j] = __shfl(bhi, poff + j);
                }
                #pragma unroll
                for (int j = 0; j < 16; j++)
                    q[j] = xb[(size_t)(klo[j] & 0xFFFFF) * 64];
                #pragma unroll
                for (int j = 0; j < 16; j += 2) {
                    a0  += bflo(khi[j])     * bflo(q[j]);
                    a1  += bfhi(khi[j])     * bfhi(q[j]);
                    a0b += bflo(khi[j + 1]) * bflo(q[j + 1]);
                    a1b += bfhi(khi[j + 1]) * bfhi(q[j + 1]);
                }
            }
            a0 += a0b; a1 += a1b;
            unsigned qn = xb[(size_t)nn[r] * 64];
            float hc0 = fmaxf(BETA * bflo(qn) + a0, 0.f);   // (1-B) folded into ef
            float hc1 = fmaxf(BETA * bfhi(qn) + a1, 0.f);
            short h, l;
            bfsplit(hc0, h, l);
            hcH[w * 4 + r][lane] = h;  hcL[w * 4 + r][lane] = l;
            bfsplit(hc1, h, l);
            hcH[w * 4 + r][64 + lane] = h;  hcL[w * 4 + r][64 + lane] = l;
        }
    }
    __syncthreads();

    // ---- phase B: wave 0 only — GEMV for all 16 rows via split-bf16 MFMA ----
    if (w == 0) {
        int quad = lane >> 4, l15 = lane & 15;
        floatx4 dacc[4] = {};
        #pragma unroll
        for (int s = 0; s < 4; s++) {
            bf16x8 aH = *(bf16x8*)&hcH[l15][quad * 8 + s * 32];
            bf16x8 aL = *(bf16x8*)&hcL[l15][quad * 8 + s * 32];
            #pragma unroll
            for (int nt = 0; nt < 4; nt++) {
                size_t wof = (size_t)(l15 + nt * 16) * 128 + quad * 8 + s * 32;
                bf16x8 bH = *(const bf16x8*)&w1h[wof];
                bf16x8 bL = *(const bf16x8*)&w1l[wof];
                dacc[nt] = __builtin_amdgcn_mfma_f32_16x16x32_bf16(aH, bH, dacc[nt], 0, 0, 0);
                dacc[nt] = __builtin_amdgcn_mfma_f32_16x16x32_bf16(aL, bH, dacc[nt], 0, 0, 0);
                dacc[nt] = __builtin_amdgcn_mfma_f32_16x16x32_bf16(aH, bL, dacc[nt], 0, 0, 0);
            }
        }
        // bias + relu: D[row=quad*4+j][o=l15+16nt]
        float h2v[4][4];                       // [nt][j], static indices
        #pragma unroll
        for (int nt = 0; nt < 4; nt++) {
            float bv = b1[l15 + nt * 16];
            #pragma unroll
            for (int j = 0; j < 4; j++)
                h2v[nt][j] = fmaxf(dacc[nt][j] + bv, 0.f);
        }
        // head: p[c][j] = sum_nt h2v[nt][j] * linW[c][l15+16nt], reduce over l15
        float pc[4][4];                        // [c][j]
        #pragma unroll
        for (int c = 0; c < 4; c++) {
            float lw0 = linS[c][l15], lw1 = linS[c][l15 + 16];
            float lw2 = linS[c][l15 + 32], lw3 = linS[c][l15 + 48];
            #pragma unroll
            for (int j = 0; j < 4; j++)
                pc[c][j] = h2v[0][j] * lw0 + h2v[1][j] * lw1
                         + h2v[2][j] * lw2 + h2v[3][j] * lw3;
        }
        #pragma unroll
        for (int off = 1; off < 16; off <<= 1) {
            #pragma unroll
            for (int c = 0; c < 4; c++)
                #pragma unroll
                for (int j = 0; j < 4; j++)
                    pc[c][j] += __shfl_xor(pc[c][j], off);
        }
        if (l15 == 0) {
            float lb0 = linb[0], lb1 = linb[1], lb2 = linb[2], lb3 = linb[3];
            #pragma unroll
            for (int j = 0; j < 4; j++) {
                int row = blockStart + quad * 4 + j;
                if (row < nrows)
                    yv[row] = make_float4(pc[0][j] + lb0, pc[1][j] + lb1,
                                          pc[2][j] + lb2, pc[3][j] + lb3);
            }
        }
    }
}

// ---------- loss: per-target 16B copy + log-softmax + mean NLL ----------
__global__ void loss_kernel(const float4* __restrict__ yv,
                            const int* __restrict__ rid,
                            const int* __restrict__ target_x,
                            const int* __restrict__ target,
                            float* __restrict__ out) {
    __shared__ float loss_s[4];
    int tid = threadIdx.x;
    int wave = tid >> 6, lane = tid & 63;
    int m = blockIdx.x * 256 + tid;
    float l = 0.f;
    if (m < M_TGT) {
        int id = rid[target_x[m]];
        float4 y = yv[id];
        *(float4*)&out[1 + (size_t)m * NUM_CLS] = y;
        float mx = fmaxf(fmaxf(y.x, y.y), fmaxf(y.z, y.w));
        float s = expf(y.x - mx) + expf(y.y - mx) + expf(y.z - mx) + expf(y.w - mx);
        float lse = mx + logf(s);
        int tg = target[m];
        float ytg = (tg == 0) ? y.x : (tg == 1) ? y.y : (tg == 2) ? y.z : y.w;
        l = lse - ytg;
    }
    #pragma unroll
    for (int off = 32; off > 0; off >>= 1) l += __shfl_xor(l, off);
    if (lane == 0) loss_s[wave] = l;
    __syncthreads();
    if (tid == 0) {
        float L = loss_s[0] + loss_s[1] + loss_s[2] + loss_s[3];
        atomicAdd(&out[0], L * (1.0f / (float)M_TGT));
    }
}

extern "C" void kernel_launch(void* const* d_in, const int* in_sizes, int n_in,
                              void* d_out, int out_size, void* d_ws, size_t ws_size,
                              hipStream_t stream) {
    const float* X           = (const float*)d_in[0];
    const float* edge_value  = (const float*)d_in[1];
    const float* Ws          = (const float*)d_in[2];
    const float* conv_weight = (const float*)d_in[3];
    const float* linear1_W   = (const float*)d_in[4];
    const float* linear1_b   = (const float*)d_in[5];
    const float* lin_W       = (const float*)d_in[6];
    const float* lin_b       = (const float*)d_in[7];
    const int*   edge_index  = (const int*)d_in[8];
    const int*   target_x    = (const int*)d_in[9];
    const int*   target      = (const int*)d_in[10];
    float* out = (float*)d_out;

    char* ws = (char*)d_ws;
    size_t off = 0;
    float* filt  = (float*)(ws + off); off += 256;
    size_t xbytes = (size_t)N_NODES * C_CH * W_OUTF * sizeof(short);  // 25.6 MB bf16
    short* Xp    = (short*)(ws + off); off += xbytes;
    float4* yv   = (float4*)(ws + off); off += (size_t)M_TGT * sizeof(float4); // 320 KB
    unsigned long long* records = (unsigned long long*)(ws + off);
    off += (size_t)M_TGT * MAXDEG * sizeof(unsigned long long);       // 15.4 MB
    short* Bt    = (short*)(ws + off); off += (size_t)C_CH * W_OUTF * W_INF * sizeof(short);
    short* w1h   = (short*)(ws + off); off += (size_t)C_CH * W_OUTF * W_OUTF * sizeof(short);
    short* w1l   = (short*)(ws + off); off += (size_t)C_CH * W_OUTF * W_OUTF * sizeof(short);
    int*   rid   = (int*)  (ws + off); off += (size_t)N_NODES * sizeof(int);
    int*   row_list = (int*)(ws + off); off += (size_t)M_TGT * sizeof(int);
    int*   counts   = (int*)(ws + off); off += (size_t)M_TGT * sizeof(int);
    int*   nrows    = (int*)(ws + off); off += 256;

    hipMemsetAsync(rid, 0xFF, (size_t)N_NODES * sizeof(int), stream);   // -1

    setup_kernel<<<128, 256, 0, stream>>>(Ws, conv_weight, linear1_W, target_x,
                                          Bt, w1h, w1l, filt, rid, nrows, out);
    compact_kernel<<<(N_NODES + 255) / 256, 256, 0, stream>>>(rid, row_list, nrows, counts);
    fused_gemm_build<<<2 * BUILD_TOT, 256, 0, stream>>>(
        X, Bt, Xp, edge_index, edge_value, filt, rid, counts, records);
    gather_kernel<<<(M_TGT + GROWS2 - 1) / GROWS2, 256, 0, stream>>>(
        row_list, counts, records, Xp, w1h, w1l, linear1_b,
        lin_W, lin_b, yv, nrows);
    loss_kernel<<<(M_TGT + 255) / 256, 256, 0, stream>>>(yv, rid, target_x, target, out);
}